// Round 5
// baseline (243.443 us; speedup 1.0000x reference)
//
#include <hip/hip_runtime.h>
#include <hip/hip_bf16.h>
#include <math.h>

#define BB 2
#define SS 2048
#define DD 1024
#define HH 16
#define HD 64
#define MM (BB * SS)   // 4096

typedef __bf16 bf16;
typedef __attribute__((ext_vector_type(8))) __bf16 bf16x8;
typedef __attribute__((ext_vector_type(4))) __bf16 bf16x4;
typedef __attribute__((ext_vector_type(4))) float f32x4;

#define QSCL 0.18033688011112042f   // log2(e)/8, folded into Q at projection

// async global->LDS, 16B per lane. LDS dest must be wave-uniform base + lane*16.
__device__ __forceinline__ void glds16(const bf16* g, bf16* l) {
    __builtin_amdgcn_global_load_lds(
        (const __attribute__((address_space(1))) void*)g,
        (__attribute__((address_space(3))) void*)l, 16, 0, 0);
}

// ---------------------------------------------------------------------------
// Prep 1: x (fp32) -> xb (bf16).  4M elements, 4/thread.
// ---------------------------------------------------------------------------
__global__ __launch_bounds__(256) void cvt_x(const float* __restrict__ x,
                                             bf16* __restrict__ xb) {
    int i = (blockIdx.x * 256 + threadIdx.x) * 4;
    float4 v = *(const float4*)(x + i);
    bf16x4 o;
    o[0] = (bf16)v.x; o[1] = (bf16)v.y; o[2] = (bf16)v.z; o[3] = (bf16)v.w;
    *(bf16x4*)(xb + i) = o;
}

// ---------------------------------------------------------------------------
// Prep 2: W[k][n] fp32 -> Wt[n][k] bf16 (4 weights via z). 64x64 LDS transpose.
// ---------------------------------------------------------------------------
__global__ __launch_bounds__(256) void cvt_w(
    const float* __restrict__ W0, const float* __restrict__ W1,
    const float* __restrict__ W2, const float* __restrict__ W3,
    bf16* __restrict__ Wt) {
    const float* W = (blockIdx.z == 0) ? W0 : (blockIdx.z == 1) ? W1
                   : (blockIdx.z == 2) ? W2 : W3;
    bf16* dst = Wt + (size_t)blockIdx.z * DD * DD;

    __shared__ float T[64][65];
    int k0 = blockIdx.y * 64, n0 = blockIdx.x * 64;
    int tr = threadIdx.x >> 4, tc = (threadIdx.x & 15) * 4;
#pragma unroll
    for (int u = 0; u < 4; u++) {
        int r = tr + u * 16;
        float4 v = *(const float4*)&W[(size_t)(k0 + r) * DD + n0 + tc];
        T[tc + 0][r] = v.x; T[tc + 1][r] = v.y;
        T[tc + 2][r] = v.z; T[tc + 3][r] = v.w;
    }
    __syncthreads();
#pragma unroll
    for (int u = 0; u < 4; u++) {
        int r = tr + u * 16;   // n index
        bf16x4 o;
        o[0] = (bf16)T[r][tc + 0]; o[1] = (bf16)T[r][tc + 1];
        o[2] = (bf16)T[r][tc + 2]; o[3] = (bf16)T[r][tc + 3];
        *(bf16x4*)&dst[(size_t)(n0 + r) * DD + k0 + tc] = o;
    }
}

// ---------------------------------------------------------------------------
// MFMA GEMM: C[m][n] = sum_k A[m][k] * Wt[n][k] + bias[n]
// 128x128 tile, BK=64, 256 threads (4 waves, each 64x64). XOR-swizzled LDS.
// Operand roles swapped (A-frag = Wt rows, B-frag = x rows) so each lane's
// C/D holds 4 consecutive n at fixed m -> vectorized epilogue stores.
//   z=0: Q out, scaled by QSCL (bf16, [token][n])
//   z=1: K out (bf16, [token][n])
//   z=2: V out written TRANSPOSED into Vt[bh][d][s]
//   ofp32 != null: fp32 out [token][n] (output projection; z must be 0)
// ---------------------------------------------------------------------------
__global__ __launch_bounds__(256) void mfma_gemm(
    const bf16* __restrict__ A, const bf16* __restrict__ Wt0,
    const float* __restrict__ b0, const float* __restrict__ b1,
    const float* __restrict__ b2,
    bf16* __restrict__ Qb, bf16* __restrict__ Kb, bf16* __restrict__ Vtg,
    float* __restrict__ ofp32) {
    const int z = blockIdx.z;
    const bf16* Wt = Wt0 + (size_t)z * DD * DD;
    const float* bias = (z == 0) ? b0 : (z == 1) ? b1 : b2;

    __shared__ __align__(16) bf16 As[128 * 64];
    __shared__ __align__(16) bf16 Bs[128 * 64];

    const int tid = threadIdx.x;
    const int lane = tid & 63;
    const int w = tid >> 6;
    const int l15 = lane & 15, quad = lane >> 4;
    const int m0 = blockIdx.y * 128;
    const int n0 = blockIdx.x * 128;
    const int mw = (w & 1) * 64;
    const int nw = (w >> 1) * 64;

    f32x4 acc[4][4];
#pragma unroll
    for (int i = 0; i < 4; i++)
#pragma unroll
        for (int j = 0; j < 4; j++) acc[i][j] = (f32x4){0.f, 0.f, 0.f, 0.f};

    for (int kt = 0; kt < DD; kt += 64) {
        __syncthreads();
#pragma unroll
        for (int u = 0; u < 4; u++) {
            int j = tid + u * 256;          // chunk 0..1023
            int row = j >> 3, cp = j & 7;
            int c = cp ^ (row & 7);         // global 16B-chunk within row
            glds16(A  + (size_t)(m0 + row) * DD + kt + c * 8, &As[j * 8]);
            glds16(Wt + (size_t)(n0 + row) * DD + kt + c * 8, &Bs[j * 8]);
        }
        __syncthreads();

#pragma unroll
        for (int kh = 0; kh < 2; kh++) {
            bf16x8 wf[4], xf[4];
#pragma unroll
            for (int i = 0; i < 4; i++) {
                int rb = nw + i * 16 + l15;
                int jb = rb * 8 + ((kh * 4 + quad) ^ (rb & 7));
                wf[i] = *(const bf16x8*)&Bs[jb * 8];
                int ra = mw + i * 16 + l15;
                int ja = ra * 8 + ((kh * 4 + quad) ^ (ra & 7));
                xf[i] = *(const bf16x8*)&As[ja * 8];
            }
#pragma unroll
            for (int i = 0; i < 4; i++)
#pragma unroll
                for (int j = 0; j < 4; j++)
                    acc[i][j] = __builtin_amdgcn_mfma_f32_16x16x32_bf16(
                        wf[i], xf[j], acc[i][j], 0, 0, 0);
        }
    }

    // acc[i][j][r]  ->  m = m0+mw+j*16+l15 (fixed per lane),
    //                   n = n0+nw+i*16+quad*4+r (4 consecutive)
    if (ofp32) {
#pragma unroll
        for (int i = 0; i < 4; i++) {
            int nb4 = n0 + nw + i * 16 + quad * 4;
            float4 b4 = *(const float4*)&bias[nb4];
#pragma unroll
            for (int j = 0; j < 4; j++) {
                int m = m0 + mw + j * 16 + l15;
                float4 o;
                o.x = acc[i][j][0] + b4.x;
                o.y = acc[i][j][1] + b4.y;
                o.z = acc[i][j][2] + b4.z;
                o.w = acc[i][j][3] + b4.w;
                *(float4*)&ofp32[(size_t)m * DD + nb4] = o;
            }
        }
    } else if (z == 2) {
        // V^T epilogue: Vt[((b*16+h)*64+d)*SS + s]
#pragma unroll
        for (int i = 0; i < 4; i++) {
            int nb4 = n0 + nw + i * 16 + quad * 4;
            float4 b4f = *(const float4*)&bias[nb4];
            float b4[4] = {b4f.x, b4f.y, b4f.z, b4f.w};
#pragma unroll
            for (int j = 0; j < 4; j++) {
                int m = m0 + mw + j * 16 + l15;
                int bb = m >> 11, s = m & (SS - 1);
#pragma unroll
                for (int r = 0; r < 4; r++) {
                    int dg = nb4 + r;          // global d index 0..1023
                    // (bb*16 + h)*64 + d == bb*1024 + dg
                    Vtg[((size_t)bb * 1024 + dg) * SS + s] =
                        (bf16)(acc[i][j][r] + b4[r]);
                }
            }
        }
    } else {
        bf16* dst = (z == 0) ? Qb : Kb;
        const float scl = (z == 0) ? QSCL : 1.0f;
#pragma unroll
        for (int i = 0; i < 4; i++) {
            int nb4 = n0 + nw + i * 16 + quad * 4;
            float4 b4 = *(const float4*)&bias[nb4];
#pragma unroll
            for (int j = 0; j < 4; j++) {
                int m = m0 + mw + j * 16 + l15;
                bf16x4 o;
                o[0] = (bf16)((acc[i][j][0] + b4.x) * scl);
                o[1] = (bf16)((acc[i][j][1] + b4.y) * scl);
                o[2] = (bf16)((acc[i][j][2] + b4.z) * scl);
                o[3] = (bf16)((acc[i][j][3] + b4.w) * scl);
                *(bf16x4*)&dst[(size_t)m * DD + nb4] = o;
            }
        }
    }
}

// ---------------------------------------------------------------------------
// MFMA flash attention, no-max softmax, fully swizzled LDS, 64-query tile.
// grid (S/64=32, B*H=32), 256 threads (4 waves). Wave w owns queries
// w*16..w*16+15, iterates all keys in 64-key tiles. Q arrives pre-scaled
// by log2(e)/8, so p = exp2(score) directly.
//   scores:  S^T tile = K(rows) x Q(cols)    -> lane holds q=l15, 16 keys
//   PV:      O = P(rows q) x V^T-as-B(n=d)   -> lane holds q=quad*4+r, d=l15
// ---------------------------------------------------------------------------
__global__ __launch_bounds__(256) void mfma_attn(
    const bf16* __restrict__ Qb, const bf16* __restrict__ Kb,
    const bf16* __restrict__ Vtg, bf16* __restrict__ ctxb) {
    __shared__ __align__(16) bf16 Qs[64 * 64];    // [q][d]  swizzled chunks
    __shared__ __align__(16) bf16 Ks[64 * 64];    // [key][d] swizzled
    __shared__ __align__(16) bf16 Vs[64 * 64];    // [d][key] swizzled
    __shared__ __align__(16) bf16 Ps[4][16 * 64]; // per-wave [q][key] swizzled

    const int tid = threadIdx.x;
    const int lane = tid & 63;
    const int w = tid >> 6;
    const int l15 = lane & 15, quad = lane >> 4;
    const int bh = blockIdx.y;
    const int b = bh >> 4, h = bh & 15;
    const int q0 = blockIdx.x * 64;
    const size_t mb = (size_t)b * SS;
    const int hc = h * HD;
    const bf16* Vt_bh = Vtg + (size_t)bh * HD * SS;
    bf16* Pw = &Ps[w][0];

    // ---- stage Q once (async, swizzled) ----
#pragma unroll
    for (int u = 0; u < 2; u++) {
        int j = tid + u * 256;              // chunk 0..511
        int row = j >> 3, cp = j & 7;
        int c = cp ^ (row & 7);
        glds16(Qb + (mb + q0 + row) * DD + hc + c * 8, &Qs[j * 8]);
    }
    __syncthreads();

    // Q fragments in registers for the whole kernel (B operand, n=q)
    bf16x8 qf[2];
    {
        int rq = w * 16 + l15;
#pragma unroll
        for (int kh = 0; kh < 2; kh++) {
            int jq = rq * 8 + ((kh * 4 + quad) ^ (rq & 7));
            qf[kh] = *(const bf16x8*)&Qs[jq * 8];
        }
    }

    float l_cur = 0.0f;
    f32x4 o[4];
#pragma unroll
    for (int nb = 0; nb < 4; nb++) o[nb] = (f32x4){0.f, 0.f, 0.f, 0.f};

    // loop-invariant Ps addresses
    int pw_off[4];
#pragma unroll
    for (int kb = 0; kb < 4; kb++) {
        int cw = kb * 2 + (quad >> 1);                       // 16B chunk
        pw_off[kb] = l15 * 64 + ((cw ^ (l15 & 7)) << 3) + (quad & 1) * 4;
    }

    for (int kt = 0; kt < SS; kt += 64) {
        __syncthreads();   // all waves done reading Ks/Vs from prev iter
        // ---- stage K and V^T tiles (async, swizzled) ----
#pragma unroll
        for (int u = 0; u < 2; u++) {
            int j = tid + u * 256;
            int row = j >> 3, cp = j & 7;
            int c = cp ^ (row & 7);
            glds16(Kb + (mb + kt + row) * DD + hc + c * 8, &Ks[j * 8]);
            glds16(Vt_bh + (size_t)row * SS + kt + c * 8, &Vs[j * 8]);
        }
        __syncthreads();

        // ---- scores: S^T tiles (A = K rows, B = Q) ----
        f32x4 sc[4];
#pragma unroll
        for (int kb = 0; kb < 4; kb++) sc[kb] = (f32x4){0.f, 0.f, 0.f, 0.f};
#pragma unroll
        for (int kb = 0; kb < 4; kb++) {
            int rk = kb * 16 + l15;
#pragma unroll
            for (int kh = 0; kh < 2; kh++) {
                int jk = rk * 8 + ((kh * 4 + quad) ^ (rk & 7));
                bf16x8 kf = *(const bf16x8*)&Ks[jk * 8];
                sc[kb] = __builtin_amdgcn_mfma_f32_16x16x32_bf16(
                    kf, qf[kh], sc[kb], 0, 0, 0);
            }
        }

        // ---- no-max softmax: p = exp2(score); accumulate row sum ----
        float rsum = 0.f;
#pragma unroll
        for (int kb = 0; kb < 4; kb++) {
            bf16x4 pvec;
#pragma unroll
            for (int r = 0; r < 4; r++) {
                float p = exp2f(sc[kb][r]);
                rsum += p;
                pvec[r] = (bf16)p;
            }
            *(bf16x4*)&Pw[pw_off[kb]] = pvec;
        }
        rsum += __shfl_xor(rsum, 16, 64);
        rsum += __shfl_xor(rsum, 32, 64);
        l_cur += rsum;

        // ---- PV: A = P (m=q), B = V^T (k=key, n=d) ----
#pragma unroll
        for (int kh = 0; kh < 2; kh++) {
            bf16x8 pf = *(const bf16x8*)&Pw[l15 * 64 + (((kh * 4 + quad) ^ (l15 & 7)) << 3)];
#pragma unroll
            for (int nb = 0; nb < 4; nb++) {
                int rv = nb * 16 + l15;
                int jv = rv * 8 + ((kh * 4 + quad) ^ (rv & 7));
                bf16x8 vf = *(const bf16x8*)&Vs[jv * 8];
                o[nb] = __builtin_amdgcn_mfma_f32_16x16x32_bf16(
                    pf, vf, o[nb], 0, 0, 0);
            }
        }
    }

    // ---- finalize: divide by row sum, store ctx bf16 ----
    float linv = 1.0f / l_cur;
    float li[4];
#pragma unroll
    for (int r = 0; r < 4; r++) li[r] = __shfl(linv, quad * 4 + r, 64);
#pragma unroll
    for (int nb = 0; nb < 4; nb++)
#pragma unroll
        for (int r = 0; r < 4; r++) {
            int qrow = q0 + w * 16 + quad * 4 + r;
            ctxb[(mb + qrow) * DD + hc + nb * 16 + l15] = (bf16)(o[nb][r] * li[r]);
        }
}

// ---------------------------------------------------------------------------
extern "C" void kernel_launch(void* const* d_in, const int* in_sizes, int n_in,
                              void* d_out, int out_size, void* d_ws, size_t ws_size,
                              hipStream_t stream) {
    const float* x  = (const float*)d_in[0];
    const float* Wq = (const float*)d_in[1];
    const float* bq = (const float*)d_in[2];
    const float* Wk = (const float*)d_in[3];
    const float* bk = (const float*)d_in[4];
    const float* Wv = (const float*)d_in[5];
    const float* bv = (const float*)d_in[6];
    const float* Wo = (const float*)d_in[7];
    const float* bo = (const float*)d_in[8];
    float* out = (float*)d_out;

    char* base = (char*)d_ws;
    bf16* xb   = (bf16*)(base);                        //  8 MB
    bf16* Wt   = (bf16*)(base + (8ull  << 20));        //  4 x 2 MB
    bf16* Qb   = (bf16*)(base + (16ull << 20));        //  8 MB (pre-scaled)
    bf16* Kb   = (bf16*)(base + (24ull << 20));        //  8 MB
    bf16* Vtg  = (bf16*)(base + (32ull << 20));        //  8 MB ([bh][d][s])
    bf16* ctxb = (bf16*)(base + (40ull << 20));        //  8 MB

    cvt_x<<<dim3((MM * DD) / (256 * 4)), dim3(256), 0, stream>>>(x, xb);
    cvt_w<<<dim3(16, 16, 4), dim3(256), 0, stream>>>(Wq, Wk, Wv, Wo, Wt);

    mfma_gemm<<<dim3(DD / 128, MM / 128, 3), dim3(256), 0, stream>>>(
        xb, Wt, bq, bk, bv, Qb, Kb, Vtg, nullptr);

    mfma_attn<<<dim3(SS / 64, BB * HH), dim3(256), 0, stream>>>(Qb, Kb, Vtg, ctxb);

    mfma_gemm<<<dim3(DD / 128, MM / 128, 1), dim3(256), 0, stream>>>(
        ctxb, Wt + 3ull * DD * DD, bo, bo, bo, nullptr, nullptr, nullptr, out);
}

// Round 6
// 235.605 us; speedup vs baseline: 1.0333x; 1.0333x over previous
//
#include <hip/hip_runtime.h>
#include <hip/hip_bf16.h>
#include <math.h>

#define BB 2
#define SS 2048
#define DD 1024
#define HH 16
#define HD 64
#define MM (BB * SS)   // 4096

typedef __bf16 bf16;
typedef __attribute__((ext_vector_type(8))) __bf16 bf16x8;
typedef __attribute__((ext_vector_type(4))) __bf16 bf16x4;
typedef __attribute__((ext_vector_type(4))) float f32x4;
typedef __attribute__((ext_vector_type(16))) float f32x16;

#define QSCL 0.18033688011112042f   // log2(e)/8, folded into Q at projection

// async global->LDS, 16B per lane. LDS dest must be wave-uniform base + lane*16.
__device__ __forceinline__ void glds16(const bf16* g, bf16* l) {
    __builtin_amdgcn_global_load_lds(
        (const __attribute__((address_space(1))) void*)g,
        (__attribute__((address_space(3))) void*)l, 16, 0, 0);
}

// ---------------------------------------------------------------------------
// Prep 1: x (fp32) -> xb (bf16).  4M elements, 4/thread.
// ---------------------------------------------------------------------------
__global__ __launch_bounds__(256) void cvt_x(const float* __restrict__ x,
                                             bf16* __restrict__ xb) {
    int i = (blockIdx.x * 256 + threadIdx.x) * 4;
    float4 v = *(const float4*)(x + i);
    bf16x4 o;
    o[0] = (bf16)v.x; o[1] = (bf16)v.y; o[2] = (bf16)v.z; o[3] = (bf16)v.w;
    *(bf16x4*)(xb + i) = o;
}

// ---------------------------------------------------------------------------
// Prep 2: W[k][n] fp32 -> Wt[n][k] bf16 (4 weights via z). 64x64 LDS transpose.
// ---------------------------------------------------------------------------
__global__ __launch_bounds__(256) void cvt_w(
    const float* __restrict__ W0, const float* __restrict__ W1,
    const float* __restrict__ W2, const float* __restrict__ W3,
    bf16* __restrict__ Wt) {
    const float* W = (blockIdx.z == 0) ? W0 : (blockIdx.z == 1) ? W1
                   : (blockIdx.z == 2) ? W2 : W3;
    bf16* dst = Wt + (size_t)blockIdx.z * DD * DD;

    __shared__ float T[64][65];
    int k0 = blockIdx.y * 64, n0 = blockIdx.x * 64;
    int tr = threadIdx.x >> 4, tc = (threadIdx.x & 15) * 4;
#pragma unroll
    for (int u = 0; u < 4; u++) {
        int r = tr + u * 16;
        float4 v = *(const float4*)&W[(size_t)(k0 + r) * DD + n0 + tc];
        T[tc + 0][r] = v.x; T[tc + 1][r] = v.y;
        T[tc + 2][r] = v.z; T[tc + 3][r] = v.w;
    }
    __syncthreads();
#pragma unroll
    for (int u = 0; u < 4; u++) {
        int r = tr + u * 16;   // n index
        bf16x4 o;
        o[0] = (bf16)T[r][tc + 0]; o[1] = (bf16)T[r][tc + 1];
        o[2] = (bf16)T[r][tc + 2]; o[3] = (bf16)T[r][tc + 3];
        *(bf16x4*)&dst[(size_t)(n0 + r) * DD + k0 + tc] = o;
    }
}

// ---------------------------------------------------------------------------
// Prep 3: V [token][h*64+d] bf16 -> Vt_g [bh][d][s] bf16 (per-head transpose).
// grid (S/64=32, BH=32), 256 threads.
// ---------------------------------------------------------------------------
__global__ __launch_bounds__(256) void vt_kernel(const bf16* __restrict__ V,
                                                 bf16* __restrict__ Vt) {
    const int bh = blockIdx.y;
    const int b = bh >> 4, h = bh & 15;
    const int s0 = blockIdx.x * 64;

    __shared__ bf16 T[64][72];
    const int r = threadIdx.x >> 2;            // 0..63
    const int c0 = (threadIdx.x & 3) * 16;     // 0,16,32,48

    const bf16* src = V + ((size_t)(b * SS + s0 + r)) * DD + h * HD + c0;
    *(bf16x8*)&T[r][c0]     = *(const bf16x8*)(src);
    *(bf16x8*)&T[r][c0 + 8] = *(const bf16x8*)(src + 8);
    __syncthreads();

    bf16x8 o0, o1;
#pragma unroll
    for (int i = 0; i < 8; i++) o0[i] = T[c0 + i][r];
#pragma unroll
    for (int i = 0; i < 8; i++) o1[i] = T[c0 + 8 + i][r];
    bf16* dst = Vt + ((size_t)bh * HD + r) * SS + s0 + c0;
    *(bf16x8*)dst       = o0;
    *(bf16x8*)(dst + 8) = o1;
}

// ---------------------------------------------------------------------------
// MFMA GEMM (R3 form): C[m][n] = sum_k A[m][k] * Wt[n][k] + bias[n]
// 128x128 tile, BK=64, 256 threads (4 waves, each 64x64). XOR-swizzled LDS.
// z selects weight/bias/dst for QKV (z=0 output scaled by QSCL);
// ofp32 != null -> fp32 output (out proj).
// ---------------------------------------------------------------------------
__global__ __launch_bounds__(256) void mfma_gemm(
    const bf16* __restrict__ A, const bf16* __restrict__ Wt0,
    const float* __restrict__ b0, const float* __restrict__ b1,
    const float* __restrict__ b2,
    bf16* __restrict__ o0, bf16* __restrict__ o1, bf16* __restrict__ o2,
    float* __restrict__ ofp32) {
    const int z = blockIdx.z;
    const bf16* Wt = Wt0 + (size_t)z * DD * DD;
    const float* bias = (z == 0) ? b0 : (z == 1) ? b1 : b2;
    bf16* dstb = (z == 0) ? o0 : (z == 1) ? o1 : o2;
    const float scl = (z == 0 && !ofp32) ? QSCL : 1.0f;

    __shared__ __align__(16) bf16 As[128 * 64];
    __shared__ __align__(16) bf16 Bs[128 * 64];

    const int tid = threadIdx.x;
    const int lane = tid & 63;
    const int w = tid >> 6;
    const int l15 = lane & 15, quad = lane >> 4;
    const int m0 = blockIdx.y * 128;
    const int n0 = blockIdx.x * 128;
    const int mw = (w & 1) * 64;
    const int nw = (w >> 1) * 64;

    f32x4 acc[4][4];
#pragma unroll
    for (int i = 0; i < 4; i++)
#pragma unroll
        for (int j = 0; j < 4; j++) acc[i][j] = (f32x4){0.f, 0.f, 0.f, 0.f};

    for (int kt = 0; kt < DD; kt += 64) {
        __syncthreads();
#pragma unroll
        for (int u = 0; u < 4; u++) {
            int j = tid + u * 256;          // chunk 0..1023
            int row = j >> 3, cp = j & 7;
            int c = cp ^ (row & 7);         // global 16B-chunk within row
            glds16(A  + (size_t)(m0 + row) * DD + kt + c * 8, &As[j * 8]);
            glds16(Wt + (size_t)(n0 + row) * DD + kt + c * 8, &Bs[j * 8]);
        }
        __syncthreads();

#pragma unroll
        for (int kh = 0; kh < 2; kh++) {
            bf16x8 af[4], bf[4];
#pragma unroll
            for (int i = 0; i < 4; i++) {
                int ra = mw + i * 16 + l15;
                int ja = ra * 8 + ((kh * 4 + quad) ^ (ra & 7));
                af[i] = *(const bf16x8*)&As[ja * 8];
                int rb = nw + i * 16 + l15;
                int jb = rb * 8 + ((kh * 4 + quad) ^ (rb & 7));
                bf[i] = *(const bf16x8*)&Bs[jb * 8];
            }
#pragma unroll
            for (int i = 0; i < 4; i++)
#pragma unroll
                for (int j = 0; j < 4; j++)
                    acc[i][j] = __builtin_amdgcn_mfma_f32_16x16x32_bf16(
                        af[i], bf[j], acc[i][j], 0, 0, 0);
        }
    }

    float bcol[4];
#pragma unroll
    for (int j = 0; j < 4; j++) bcol[j] = bias[n0 + nw + j * 16 + l15];

    if (ofp32) {
#pragma unroll
        for (int i = 0; i < 4; i++)
#pragma unroll
            for (int j = 0; j < 4; j++)
#pragma unroll
                for (int r = 0; r < 4; r++) {
                    int row = m0 + mw + i * 16 + quad * 4 + r;
                    int col = n0 + nw + j * 16 + l15;
                    ofp32[(size_t)row * DD + col] = acc[i][j][r] + bcol[j];
                }
    } else {
#pragma unroll
        for (int i = 0; i < 4; i++)
#pragma unroll
            for (int j = 0; j < 4; j++)
#pragma unroll
                for (int r = 0; r < 4; r++) {
                    int row = m0 + mw + i * 16 + quad * 4 + r;
                    int col = n0 + nw + j * 16 + l15;
                    dstb[(size_t)row * DD + col] =
                        (bf16)((acc[i][j][r] + bcol[j]) * scl);
                }
    }
}

// ---------------------------------------------------------------------------
// MFMA flash attention, 32x32x16 shape, no-max softmax, swizzled LDS.
// grid (S/64=32, B*H=32), 128 threads (2 waves). Wave w owns queries
// w*32..w*32+31; iterates all keys in 64-key tiles. Q pre-scaled by log2e/8.
//   scores: S^T = K(rows,A) x Q(cols,B): lane q=l31, 32 keys in C regs
//   PV:     O = P(A, m=q) x V^T(B, n=d):  lane d=db*32+l31, 16 q-rows in C
// A/B frag: elem k = (lane>>5)*8 + j.  C/D: col=lane&31,
// row=(reg&3)+8*(reg>>2)+4*(lane>>5)  [m74/m101 verified].
// ---------------------------------------------------------------------------
__global__ __launch_bounds__(128) void mfma_attn(
    const bf16* __restrict__ Qb, const bf16* __restrict__ Kb,
    const bf16* __restrict__ Vtg, bf16* __restrict__ ctxb) {
    __shared__ __align__(16) bf16 Qs[64 * 64];    // [q][d]   swizzled chunks
    __shared__ __align__(16) bf16 Ks[64 * 64];    // [key][d] swizzled
    __shared__ __align__(16) bf16 Vs[64 * 64];    // [d][key] swizzled
    __shared__ __align__(16) bf16 Ps[2][32 * 64]; // per-wave [q][key] swizzled

    const int tid = threadIdx.x;
    const int lane = tid & 63;
    const int w = tid >> 6;            // 0..1
    const int l31 = lane & 31, hi = lane >> 5;
    const int bh = blockIdx.y;
    const int b = bh >> 4, h = bh & 15;
    const int q0 = blockIdx.x * 64;
    const size_t mb = (size_t)b * SS;
    const int hc = h * HD;
    const bf16* Vt_bh = Vtg + (size_t)bh * HD * SS;
    bf16* Pw = &Ps[w][0];

    // ---- stage Q once (async, swizzled): 512 chunks over 128 threads ----
#pragma unroll
    for (int u = 0; u < 4; u++) {
        int j = tid + u * 128;              // chunk 0..511
        int row = j >> 3, cp = j & 7;
        int c = cp ^ (row & 7);
        glds16(Qb + (mb + q0 + row) * DD + hc + c * 8, &Qs[j * 8]);
    }
    __syncthreads();

    // Q fragments in registers for the whole kernel (B operand, n=q)
    bf16x8 qf[4];
    {
        int rq = w * 32 + l31;
#pragma unroll
        for (int t = 0; t < 4; t++) {
            int jq = rq * 8 + ((t * 2 + hi) ^ (rq & 7));
            qf[t] = *(const bf16x8*)&Qs[jq * 8];
        }
    }

    float l_cur = 0.0f;
    f32x16 o[2];
#pragma unroll
    for (int db = 0; db < 2; db++)
#pragma unroll
        for (int r = 0; r < 16; r++) o[db][r] = 0.f;

    for (int kt = 0; kt < SS; kt += 64) {
        __syncthreads();   // all waves done reading Ks/Vs from prev iter
        // ---- stage K and V^T tiles (async, swizzled): 512 chunks each ----
#pragma unroll
        for (int u = 0; u < 4; u++) {
            int j = tid + u * 128;
            int row = j >> 3, cp = j & 7;
            int c = cp ^ (row & 7);
            glds16(Kb + (mb + kt + row) * DD + hc + c * 8, &Ks[j * 8]);
            glds16(Vt_bh + (size_t)row * SS + kt + c * 8, &Vs[j * 8]);
        }
        __syncthreads();

        // ---- scores: S^T = K x Q, two 32-key blocks, 4 k-steps of 16 ----
        f32x16 sc[2];
#pragma unroll
        for (int kb = 0; kb < 2; kb++)
#pragma unroll
            for (int r = 0; r < 16; r++) sc[kb][r] = 0.f;
#pragma unroll
        for (int kb = 0; kb < 2; kb++) {
            int rk = kb * 32 + l31;
#pragma unroll
            for (int t = 0; t < 4; t++) {
                int jk = rk * 8 + ((t * 2 + hi) ^ (rk & 7));
                bf16x8 kf = *(const bf16x8*)&Ks[jk * 8];
                sc[kb] = __builtin_amdgcn_mfma_f32_32x32x16_bf16(
                    kf, qf[t], sc[kb], 0, 0, 0);
            }
        }

        // ---- no-max softmax: p = exp2(score); write P to per-wave LDS ----
        // lane's q = l31; reg g2*4+rr -> key kb*32 + g2*8 + hi*4 + rr
        float rsum = 0.f;
#pragma unroll
        for (int kb = 0; kb < 2; kb++) {
#pragma unroll
            for (int g2 = 0; g2 < 4; g2++) {
                bf16x4 pvec;
#pragma unroll
                for (int rr = 0; rr < 4; rr++) {
                    float p = exp2f(sc[kb][g2 * 4 + rr]);
                    rsum += p;
                    pvec[rr] = (bf16)p;
                }
                int cw = (kb * 4 + g2) ^ (l31 & 7);
                *(bf16x4*)&Pw[l31 * 64 + cw * 8 + hi * 4] = pvec;
            }
        }
        rsum += __shfl_xor(rsum, 32, 64);
        l_cur += rsum;

        // ---- PV: A = P (m=q), B = V^T (k=key, n=d) ----
#pragma unroll
        for (int t = 0; t < 4; t++) {
            int cpp = (t * 2 + hi) ^ (l31 & 7);
            bf16x8 pf = *(const bf16x8*)&Pw[l31 * 64 + cpp * 8];
#pragma unroll
            for (int db = 0; db < 2; db++) {
                int dv = db * 32 + l31;
                int jv = dv * 8 + ((t * 2 + hi) ^ (dv & 7));
                bf16x8 vf = *(const bf16x8*)&Vs[jv * 8];
                o[db] = __builtin_amdgcn_mfma_f32_32x32x16_bf16(
                    pf, vf, o[db], 0, 0, 0);
            }
        }
    }

    // ---- finalize: divide by row sum, store ctx bf16 ----
    float linv = 1.0f / l_cur;
#pragma unroll
    for (int r = 0; r < 16; r++) {
        int ql = (r & 3) + 8 * (r >> 2) + 4 * hi;   // local q row 0..31
        float li = __shfl(linv, ql, 64);
        int qrow = q0 + w * 32 + ql;
#pragma unroll
        for (int db = 0; db < 2; db++) {
            ctxb[(mb + qrow) * DD + hc + db * 32 + l31] = (bf16)(o[db][r] * li);
        }
    }
}

// ---------------------------------------------------------------------------
extern "C" void kernel_launch(void* const* d_in, const int* in_sizes, int n_in,
                              void* d_out, int out_size, void* d_ws, size_t ws_size,
                              hipStream_t stream) {
    const float* x  = (const float*)d_in[0];
    const float* Wq = (const float*)d_in[1];
    const float* bq = (const float*)d_in[2];
    const float* Wk = (const float*)d_in[3];
    const float* bk = (const float*)d_in[4];
    const float* Wv = (const float*)d_in[5];
    const float* bv = (const float*)d_in[6];
    const float* Wo = (const float*)d_in[7];
    const float* bo = (const float*)d_in[8];
    float* out = (float*)d_out;

    char* base = (char*)d_ws;
    bf16* xb   = (bf16*)(base);                        //  8 MB (dead after QKV gemm)
    bf16* Wt   = (bf16*)(base + (8ull  << 20));        //  4 x 2 MB
    bf16* Qb   = (bf16*)(base + (16ull << 20));        //  8 MB (pre-scaled)
    bf16* Kb   = (bf16*)(base + (24ull << 20));        //  8 MB
    bf16* Vb   = (bf16*)(base + (32ull << 20));        //  8 MB
    bf16* ctxb = (bf16*)(base + (40ull << 20));        //  8 MB
    bf16* Vtg  = xb;                                   //  reuse xb region

    cvt_x<<<dim3((MM * DD) / (256 * 4)), dim3(256), 0, stream>>>(x, xb);
    cvt_w<<<dim3(16, 16, 4), dim3(256), 0, stream>>>(Wq, Wk, Wv, Wo, Wt);

    mfma_gemm<<<dim3(DD / 128, MM / 128, 3), dim3(256), 0, stream>>>(
        xb, Wt, bq, bk, bv, Qb, Kb, Vb, nullptr);

    vt_kernel<<<dim3(SS / 64, BB * HH), dim3(256), 0, stream>>>(Vb, Vtg);

    mfma_attn<<<dim3(SS / 64, BB * HH), dim3(128), 0, stream>>>(Qb, Kb, Vtg, ctxb);

    mfma_gemm<<<dim3(DD / 128, MM / 128, 1), dim3(256), 0, stream>>>(
        ctxb, Wt + 3ull * DD * DD, bo, bo, bo, nullptr, nullptr, nullptr, out);
}